// Round 4
// baseline (88.562 us; speedup 1.0000x reference)
//
#include <hip/hip_runtime.h>
#include <math.h>

#define DIM 256

// ---------------------------------------------------------------------------
// Fully fused kernel. Phase 0 (per block): build the Pauli-transfer table
// T[q][p] in LDS (q=0..3 output qubit, p = p0*64+p1*16+p2*4+p3, pauli
// 0=I,1=X,2=Y,3=Z) such that  z_q = sum_p T[q][p] * prod_i a_i[p_i], where
// a_i is qubit i's Bloch vector after encoding+layer0 gates; depolarize is
// folded in as s^(1+nnz(P)), s = 1-4*0.05/3. Numerically accumulates
// V = prod_i (RZ_i RY_i CNOT_{i,i+1}) as 16x16 complex in LDS, then
// O_q = V^dag Z_q V, then T = Re Tr(P O_q)/16 * s^(1+nnz).
// Qubit q <-> index bit (3-q) (qubit 0 = MSB, matching the reference).
//
// Phase 1: 2 rows per wave (32 lanes/row: l=lane&31 covers 8 columns,
// g=lane>>5 selects the row). GEMV -> 5-step group reduce -> tanh+LN ->
// Bloch -> per-lane 8-string Pauli contraction -> 5-step reduce ->
// W_out epilogue + residual, x kept in registers (read once, written once).
// ---------------------------------------------------------------------------

__device__ __forceinline__ float sel3(int p, float vx, float vy, float vz)
{
  float r = 1.0f;
  r = (p == 1) ? vx : r;
  r = (p == 2) ? vy : r;
  r = (p == 3) ? vz : r;
  return r;
}

__global__ __launch_bounds__(256) void qlayer_fused_kernel(
    const float* __restrict__ x,
    const float* __restrict__ Win,
    const float* __restrict__ b_in,
    const float* __restrict__ gamma,
    const float* __restrict__ beta,
    const float* __restrict__ qw,
    const float* __restrict__ Wout,
    const float* __restrict__ b_out,
    float* __restrict__ out,
    int B)
{
  __shared__ float Vr[16][16], Vi[16][16];
  __shared__ float Or[16][16], Oi[16][16];
  __shared__ float Tl[4][256];

  const int tid = threadIdx.x;

  // ================= Phase 0: build T in LDS (validated in round 2) ========
  {
    const int r = tid >> 4, c = tid & 15;
    Vr[r][c] = (r == c) ? 1.0f : 0.0f;
    Vi[r][c] = 0.0f;
    __syncthreads();

    #pragma unroll 1
    for (int i = 0; i < 4; ++i) {
      const int cm = 8 >> i;             // control mask (qubit i)
      const int tm = 8 >> ((i + 1) & 3); // target mask (qubit (i+1)%4)
      // CNOT(control=i, target=(i+1)%4): permutation rows
      {
        const int k = (r & cm) ? (r ^ tm) : r;
        const float nr = Vr[k][c], ni = Vi[k][c];
        __syncthreads();
        Vr[r][c] = nr; Vi[r][c] = ni;
        __syncthreads();
      }
      const float w  = qw[4 + i];        // qweights[1][i]
      const float ch = cosf(0.5f * w), sh = sinf(0.5f * w);
      // RY(w) on qubit i
      {
        const int m = 8 >> i;
        const int r0 = r & ~m, r1 = r | m;
        float u0, u1;
        if (r & m) { u0 = sh; u1 = ch; } else { u0 = ch; u1 = -sh; }
        const float nr = u0 * Vr[r0][c] + u1 * Vr[r1][c];
        const float ni = u0 * Vi[r0][c] + u1 * Vi[r1][c];
        __syncthreads();
        Vr[r][c] = nr; Vi[r][c] = ni;
        __syncthreads();
      }
      // RZ(w) on qubit i (diagonal, own-element only)
      {
        const int m = 8 >> i;
        const float pr = ch;
        const float pi = (r & m) ? sh : -sh;
        const float vr = Vr[r][c], vi = Vi[r][c];
        Vr[r][c] = pr * vr - pi * vi;
        Vi[r][c] = pr * vi + pi * vr;
        __syncthreads();
      }
    }

    const float sdep = 1.0f - 4.0f * 0.05f / 3.0f;
    const int p0 = tid >> 6, p1 = (tid >> 4) & 3, p2 = (tid >> 2) & 3, p3 = tid & 3;

    #pragma unroll 1
    for (int q = 0; q < 4; ++q) {
      const int zm = 8 >> q;
      float orr = 0.0f, oii = 0.0f;
      for (int k = 0; k < 16; ++k) {
        const float sgn = (k & zm) ? -1.0f : 1.0f;
        const float ar = Vr[k][r], ai = -Vi[k][r];
        const float br = Vr[k][c], bi = Vi[k][c];
        orr += sgn * (ar * br - ai * bi);
        oii += sgn * (ar * bi + ai * br);
      }
      __syncthreads();
      Or[r][c] = orr; Oi[r][c] = oii;
      __syncthreads();

      float tr = 0.0f;
      for (int n = 0; n < 16; ++n) {
        int m = n;
        float fr = 1.0f, fi = 0.0f;
        #pragma unroll
        for (int i2 = 0; i2 < 4; ++i2) {
          const int a   = (n >> (3 - i2)) & 1;
          const int pi_ = (i2 == 0) ? p0 : (i2 == 1) ? p1 : (i2 == 2) ? p2 : p3;
          if (pi_ == 1) {                    // X
            m ^= (8 >> i2);
          } else if (pi_ == 2) {             // Y
            m ^= (8 >> i2);
            const float s2  = a ? 1.0f : -1.0f;
            const float nfr = -fi * s2, nfi = fr * s2;
            fr = nfr; fi = nfi;
          } else if (pi_ == 3) {             // Z
            if (a) { fr = -fr; fi = -fi; }
          }
        }
        tr += fr * Or[m][n] - fi * Oi[m][n];
      }
      const int nnz = (p0 != 0) + (p1 != 0) + (p2 != 0) + (p3 != 0);
      float scale = 1.0f / 16.0f;
      for (int e = 0; e <= nnz; ++e) scale *= sdep;
      Tl[q][tid] = tr * scale;
      __syncthreads();
    }
  }

  // ================= Phase 1: streaming pass, 2 rows per wave ==============
  const int lane = tid & 63;
  const int l    = lane & 31;      // lane within row group
  const int g    = lane >> 5;      // row within pair
  const int wid  = blockIdx.x * (blockDim.x >> 6) + (tid >> 6);
  const int nw   = gridDim.x * (blockDim.x >> 6);

  // hoisted per-lane fragments (constant across rows)
  float4 winf[4][2];
  #pragma unroll
  for (int q = 0; q < 4; ++q)
    #pragma unroll
    for (int k = 0; k < 2; ++k)
      winf[q][k] = *reinterpret_cast<const float4*>(&Win[q * 256 + k * 128 + l * 4]);

  float4 tf[4][2];
  #pragma unroll
  for (int q = 0; q < 4; ++q)
    #pragma unroll
    for (int k2 = 0; k2 < 2; ++k2)
      tf[q][k2] = *reinterpret_cast<const float4*>(&Tl[q][l * 8 + k2 * 4]);

  float4 woutf[2][4];
  #pragma unroll
  for (int k = 0; k < 2; ++k)
    #pragma unroll
    for (int m = 0; m < 4; ++m)
      woutf[k][m] = *reinterpret_cast<const float4*>(&Wout[(k * 128 + l * 4 + m) * 4]);

  float4 boutf[2];
  #pragma unroll
  for (int k = 0; k < 2; ++k)
    boutf[k] = *reinterpret_cast<const float4*>(&b_out[k * 128 + l * 4]);

  float bi[4], ga[4], be[4], cw0[4], sw0[4], cw1[4], sw1[4];
  #pragma unroll
  for (int i = 0; i < 4; ++i) {
    bi[i] = b_in[i]; ga[i] = gamma[i]; be[i] = beta[i];
    const float w0 = qw[i], w1 = qw[4 + i];
    cw0[i] = cosf(w0); sw0[i] = sinf(w0);
    cw1[i] = cosf(w1); sw1[i] = sinf(w1);
  }

  // per-lane Pauli indices for strings p = l*8 + k2*4 + m
  const int p0s = l >> 3;
  const int p1s = (l >> 1) & 3;
  const int p2b = (l & 1) << 1;    // p2 = p2b + k2

  const int npair = B >> 1;
  for (int pr = wid; pr < npair; pr += nw) {
    const size_t rbase = ((size_t)(pr * 2 + g)) * DIM + l * 4;
    const float4 xv0 = *reinterpret_cast<const float4*>(&x[rbase]);
    const float4 xv1 = *reinterpret_cast<const float4*>(&x[rbase + 128]);

    // ---- angles GEMV over this lane's 8 columns ----
    float acc[4];
    #pragma unroll
    for (int q = 0; q < 4; ++q) {
      acc[q] = xv0.x * winf[q][0].x + xv0.y * winf[q][0].y +
               xv0.z * winf[q][0].z + xv0.w * winf[q][0].w +
               xv1.x * winf[q][1].x + xv1.y * winf[q][1].y +
               xv1.z * winf[q][1].z + xv1.w * winf[q][1].w;
    }
    #pragma unroll
    for (int off = 1; off < 32; off <<= 1) {
      #pragma unroll
      for (int q = 0; q < 4; ++q) acc[q] += __shfl_xor(acc[q], off, 64);
    }

    // ---- tanh + LayerNorm(4) ----
    float xp[4];
    #pragma unroll
    for (int q = 0; q < 4; ++q) {
      const float e = __expf(2.0f * (acc[q] + bi[q]));
      xp[q] = 1.0f - __fdividef(2.0f, e + 1.0f);   // tanh, inf-safe
    }
    const float mu = 0.25f * (xp[0] + xp[1] + xp[2] + xp[3]);
    const float d0 = xp[0] - mu, d1 = xp[1] - mu, d2 = xp[2] - mu, d3 = xp[3] - mu;
    const float var = 0.25f * (d0 * d0 + d1 * d1 + d2 * d2 + d3 * d3);
    const float inv = rsqrtf(var + 1e-5f);

    // ---- Bloch vector per qubit after RX(t)RZ(t)RX(w0)RZ(w1) ----
    float Ax[4], Ay[4], Az[4];
    #pragma unroll
    for (int i = 0; i < 4; ++i) {
      const float ang = ((i == 0 ? d0 : i == 1 ? d1 : i == 2 ? d2 : d3) * inv) * ga[i] + be[i];
      float sn, cs;
      __sincosf(ang, &sn, &cs);
      const float ax = sn * sn;                     // RX(t) then RZ(t)
      const float ay = -sn * cs;
      const float az = cs;
      const float ay2 = ay * cw0[i] - az * sw0[i];  // RX(w0)
      const float az2 = ay * sw0[i] + az * cw0[i];
      const float ax3 = ax * cw1[i] - ay2 * sw1[i]; // RZ(w1)
      const float ay3 = ax * sw1[i] + ay2 * cw1[i];
      Ax[i] = ax3; Ay[i] = ay3; Az[i] = az2;
    }

    // ---- Pauli contraction: 8 strings per lane ----
    const float b2 = sel3(p0s, Ax[0], Ay[0], Az[0]) *
                     sel3(p1s, Ax[1], Ay[1], Az[1]);
    const float bv0 = b2 * sel3(p2b,     Ax[2], Ay[2], Az[2]);
    const float bv1 = b2 * sel3(p2b + 1, Ax[2], Ay[2], Az[2]);

    float z[4];
    #pragma unroll
    for (int q = 0; q < 4; ++q) {
      const float s0 = tf[q][0].x + tf[q][0].y * Ax[3] + tf[q][0].z * Ay[3] + tf[q][0].w * Az[3];
      const float s1 = tf[q][1].x + tf[q][1].y * Ax[3] + tf[q][1].z * Ay[3] + tf[q][1].w * Az[3];
      z[q] = bv0 * s0 + bv1 * s1;
    }
    #pragma unroll
    for (int off = 1; off < 32; off <<= 1) {
      #pragma unroll
      for (int q = 0; q < 4; ++q) z[q] += __shfl_xor(z[q], off, 64);
    }

    // ---- epilogue: out = x + z @ Wout^T + b_out ----
    float4 o0, o1;
    o0.x = xv0.x + boutf[0].x + z[0] * woutf[0][0].x + z[1] * woutf[0][0].y + z[2] * woutf[0][0].z + z[3] * woutf[0][0].w;
    o0.y = xv0.y + boutf[0].y + z[0] * woutf[0][1].x + z[1] * woutf[0][1].y + z[2] * woutf[0][1].z + z[3] * woutf[0][1].w;
    o0.z = xv0.z + boutf[0].z + z[0] * woutf[0][2].x + z[1] * woutf[0][2].y + z[2] * woutf[0][2].z + z[3] * woutf[0][2].w;
    o0.w = xv0.w + boutf[0].w + z[0] * woutf[0][3].x + z[1] * woutf[0][3].y + z[2] * woutf[0][3].z + z[3] * woutf[0][3].w;
    o1.x = xv1.x + boutf[1].x + z[0] * woutf[1][0].x + z[1] * woutf[1][0].y + z[2] * woutf[1][0].z + z[3] * woutf[1][0].w;
    o1.y = xv1.y + boutf[1].y + z[0] * woutf[1][1].x + z[1] * woutf[1][1].y + z[2] * woutf[1][1].z + z[3] * woutf[1][1].w;
    o1.z = xv1.z + boutf[1].z + z[0] * woutf[1][2].x + z[1] * woutf[1][2].y + z[2] * woutf[1][2].z + z[3] * woutf[1][2].w;
    o1.w = xv1.w + boutf[1].w + z[0] * woutf[1][3].x + z[1] * woutf[1][3].y + z[2] * woutf[1][3].z + z[3] * woutf[1][3].w;

    *reinterpret_cast<float4*>(&out[rbase])       = o0;
    *reinterpret_cast<float4*>(&out[rbase + 128]) = o1;
  }
}

extern "C" void kernel_launch(void* const* d_in, const int* in_sizes, int n_in,
                              void* d_out, int out_size, void* d_ws, size_t ws_size,
                              hipStream_t stream)
{
  const float* x     = (const float*)d_in[0];
  const float* Win   = (const float*)d_in[1];
  const float* b_in  = (const float*)d_in[2];
  const float* gamma = (const float*)d_in[3];
  const float* beta  = (const float*)d_in[4];
  const float* qw    = (const float*)d_in[5];
  const float* Wout  = (const float*)d_in[6];
  const float* b_out = (const float*)d_in[7];
  float* out = (float*)d_out;
  const int B = in_sizes[0] / DIM;

  hipLaunchKernelGGL(qlayer_fused_kernel, dim3(1024), dim3(256), 0, stream,
                     x, Win, b_in, gamma, beta, qw, Wout, b_out, out, B);
}

// Round 5
// 61.057 us; speedup vs baseline: 1.4505x; 1.4505x over previous
//
#include <hip/hip_runtime.h>
#include <math.h>

#define DIM 256

// ---------------------------------------------------------------------------
// Fully fused kernel (validated structure, round 3: passed, absmax 0.0156).
// Phase 0 (per block): build Pauli-transfer table T[q][p] in LDS.
// Phase 1: 2 rows per wave (32 lanes/row), grid-stride, x-prefetch pipeline.
// Round-5 deltas vs round-3: __launch_bounds__(256,2) to raise the VGPR cap
// (fragments register-resident; Tl read once in prologue), 512-block grid
// (2 blocks/CU), software-pipelined x loads.
// ---------------------------------------------------------------------------

__device__ __forceinline__ float sel3(int p, float vx, float vy, float vz)
{
  float r = 1.0f;
  r = (p == 1) ? vx : r;
  r = (p == 2) ? vy : r;
  r = (p == 3) ? vz : r;
  return r;
}

__global__ __launch_bounds__(256, 2) void qlayer_fused_kernel(
    const float* __restrict__ x,
    const float* __restrict__ Win,
    const float* __restrict__ b_in,
    const float* __restrict__ gamma,
    const float* __restrict__ beta,
    const float* __restrict__ qw,
    const float* __restrict__ Wout,
    const float* __restrict__ b_out,
    float* __restrict__ out,
    int B)
{
  __shared__ float Vr[16][16], Vi[16][16];
  __shared__ float Or[16][16], Oi[16][16];
  __shared__ float Tl[4][256];

  const int tid = threadIdx.x;

  // ================= Phase 0: build T in LDS (validated) ===================
  {
    const int r = tid >> 4, c = tid & 15;
    Vr[r][c] = (r == c) ? 1.0f : 0.0f;
    Vi[r][c] = 0.0f;
    __syncthreads();

    #pragma unroll 1
    for (int i = 0; i < 4; ++i) {
      const int cm = 8 >> i;             // control mask (qubit i)
      const int tm = 8 >> ((i + 1) & 3); // target mask (qubit (i+1)%4)
      // CNOT(control=i, target=(i+1)%4): row permutation
      {
        const int k = (r & cm) ? (r ^ tm) : r;
        const float nr = Vr[k][c], ni = Vi[k][c];
        __syncthreads();
        Vr[r][c] = nr; Vi[r][c] = ni;
        __syncthreads();
      }
      const float w  = qw[4 + i];        // qweights[1][i]
      const float ch = cosf(0.5f * w), sh = sinf(0.5f * w);
      // RY(w) on qubit i
      {
        const int m = 8 >> i;
        const int r0 = r & ~m, r1 = r | m;
        float u0, u1;
        if (r & m) { u0 = sh; u1 = ch; } else { u0 = ch; u1 = -sh; }
        const float nr = u0 * Vr[r0][c] + u1 * Vr[r1][c];
        const float ni = u0 * Vi[r0][c] + u1 * Vi[r1][c];
        __syncthreads();
        Vr[r][c] = nr; Vi[r][c] = ni;
        __syncthreads();
      }
      // RZ(w) on qubit i (diagonal)
      {
        const int m = 8 >> i;
        const float pr = ch;
        const float pi = (r & m) ? sh : -sh;
        const float vr = Vr[r][c], vi = Vi[r][c];
        Vr[r][c] = pr * vr - pi * vi;
        Vi[r][c] = pr * vi + pi * vr;
        __syncthreads();
      }
    }

    const float sdep = 1.0f - 4.0f * 0.05f / 3.0f;
    const int p0 = tid >> 6, p1 = (tid >> 4) & 3, p2 = (tid >> 2) & 3, p3 = tid & 3;

    #pragma unroll 1
    for (int q = 0; q < 4; ++q) {
      const int zm = 8 >> q;
      float orr = 0.0f, oii = 0.0f;
      for (int k = 0; k < 16; ++k) {
        const float sgn = (k & zm) ? -1.0f : 1.0f;
        const float ar = Vr[k][r], ai = -Vi[k][r];
        const float br = Vr[k][c], bi = Vi[k][c];
        orr += sgn * (ar * br - ai * bi);
        oii += sgn * (ar * bi + ai * br);
      }
      __syncthreads();
      Or[r][c] = orr; Oi[r][c] = oii;
      __syncthreads();

      float tr = 0.0f;
      for (int n = 0; n < 16; ++n) {
        int m = n;
        float fr = 1.0f, fi = 0.0f;
        #pragma unroll
        for (int i2 = 0; i2 < 4; ++i2) {
          const int a   = (n >> (3 - i2)) & 1;
          const int pi_ = (i2 == 0) ? p0 : (i2 == 1) ? p1 : (i2 == 2) ? p2 : p3;
          if (pi_ == 1) {                    // X
            m ^= (8 >> i2);
          } else if (pi_ == 2) {             // Y
            m ^= (8 >> i2);
            const float s2  = a ? 1.0f : -1.0f;
            const float nfr = -fi * s2, nfi = fr * s2;
            fr = nfr; fi = nfi;
          } else if (pi_ == 3) {             // Z
            if (a) { fr = -fr; fi = -fi; }
          }
        }
        tr += fr * Or[m][n] - fi * Oi[m][n];
      }
      const int nnz = (p0 != 0) + (p1 != 0) + (p2 != 0) + (p3 != 0);
      float scale = 1.0f / 16.0f;
      for (int e = 0; e <= nnz; ++e) scale *= sdep;
      Tl[q][tid] = tr * scale;
      __syncthreads();
    }
  }

  // ================= Phase 1: streaming pass, 2 rows per wave ==============
  const int lane = tid & 63;
  const int l    = lane & 31;      // lane within row group
  const int g    = lane >> 5;      // row within pair
  const int wid  = blockIdx.x * (blockDim.x >> 6) + (tid >> 6);
  const int nw   = gridDim.x * (blockDim.x >> 6);

  // hoisted per-lane fragments (constant across rows; VGPR-resident under
  // the (256,2) launch bound)
  float4 winf[4][2];
  #pragma unroll
  for (int q = 0; q < 4; ++q)
    #pragma unroll
    for (int k = 0; k < 2; ++k)
      winf[q][k] = *reinterpret_cast<const float4*>(&Win[q * 256 + k * 128 + l * 4]);

  float4 tf[4][2];
  #pragma unroll
  for (int q = 0; q < 4; ++q)
    #pragma unroll
    for (int k2 = 0; k2 < 2; ++k2)
      tf[q][k2] = *reinterpret_cast<const float4*>(&Tl[q][l * 8 + k2 * 4]);

  float4 woutf[2][4];
  #pragma unroll
  for (int k = 0; k < 2; ++k)
    #pragma unroll
    for (int m = 0; m < 4; ++m)
      woutf[k][m] = *reinterpret_cast<const float4*>(&Wout[(k * 128 + l * 4 + m) * 4]);

  float4 boutf[2];
  #pragma unroll
  for (int k = 0; k < 2; ++k)
    boutf[k] = *reinterpret_cast<const float4*>(&b_out[k * 128 + l * 4]);

  float bi[4], ga[4], be[4], cw0[4], sw0[4], cw1[4], sw1[4];
  #pragma unroll
  for (int i = 0; i < 4; ++i) {
    bi[i] = b_in[i]; ga[i] = gamma[i]; be[i] = beta[i];
    const float w0 = qw[i], w1 = qw[4 + i];
    cw0[i] = cosf(w0); sw0[i] = sinf(w0);
    cw1[i] = cosf(w1); sw1[i] = sinf(w1);
  }

  // per-lane Pauli indices for strings p = l*8 + k2*4 + m
  const int p0s = l >> 3;
  const int p1s = (l >> 1) & 3;
  const int p2b = (l & 1) << 1;    // p2 = p2b + k2

  const int npair = B >> 1;

  // ---- software pipeline: prefetch first row pair ----
  int pr = wid;
  size_t rbase = ((size_t)(pr * 2 + g)) * DIM + l * 4;
  float4 xv0, xv1;
  if (pr < npair) {
    xv0 = *reinterpret_cast<const float4*>(&x[rbase]);
    xv1 = *reinterpret_cast<const float4*>(&x[rbase + 128]);
  }

  #pragma unroll 1
  for (; pr < npair; pr += nw) {
    // prefetch next iteration's rows
    const int prn = pr + nw;
    const size_t nbase = ((size_t)(prn * 2 + g)) * DIM + l * 4;
    float4 nx0, nx1;
    if (prn < npair) {
      nx0 = *reinterpret_cast<const float4*>(&x[nbase]);
      nx1 = *reinterpret_cast<const float4*>(&x[nbase + 128]);
    }

    // ---- angles GEMV over this lane's 8 columns ----
    float acc[4];
    #pragma unroll
    for (int q = 0; q < 4; ++q) {
      acc[q] = xv0.x * winf[q][0].x + xv0.y * winf[q][0].y +
               xv0.z * winf[q][0].z + xv0.w * winf[q][0].w +
               xv1.x * winf[q][1].x + xv1.y * winf[q][1].y +
               xv1.z * winf[q][1].z + xv1.w * winf[q][1].w;
    }
    #pragma unroll
    for (int off = 1; off < 32; off <<= 1) {
      #pragma unroll
      for (int q = 0; q < 4; ++q) acc[q] += __shfl_xor(acc[q], off, 64);
    }

    // ---- tanh + LayerNorm(4) ----
    float xp[4];
    #pragma unroll
    for (int q = 0; q < 4; ++q) {
      const float e = __expf(2.0f * (acc[q] + bi[q]));
      xp[q] = 1.0f - __fdividef(2.0f, e + 1.0f);   // tanh, inf-safe
    }
    const float mu = 0.25f * (xp[0] + xp[1] + xp[2] + xp[3]);
    const float d0 = xp[0] - mu, d1 = xp[1] - mu, d2 = xp[2] - mu, d3 = xp[3] - mu;
    const float var = 0.25f * (d0 * d0 + d1 * d1 + d2 * d2 + d3 * d3);
    const float inv = rsqrtf(var + 1e-5f);

    // ---- Bloch vector per qubit after RX(t)RZ(t)RX(w0)RZ(w1) ----
    float Ax[4], Ay[4], Az[4];
    #pragma unroll
    for (int i = 0; i < 4; ++i) {
      const float ang = ((i == 0 ? d0 : i == 1 ? d1 : i == 2 ? d2 : d3) * inv) * ga[i] + be[i];
      float sn, cs;
      __sincosf(ang, &sn, &cs);
      const float ax = sn * sn;                     // RX(t) then RZ(t)
      const float ay = -sn * cs;
      const float az = cs;
      const float ay2 = ay * cw0[i] - az * sw0[i];  // RX(w0)
      const float az2 = ay * sw0[i] + az * cw0[i];
      const float ax3 = ax * cw1[i] - ay2 * sw1[i]; // RZ(w1)
      const float ay3 = ax * sw1[i] + ay2 * cw1[i];
      Ax[i] = ax3; Ay[i] = ay3; Az[i] = az2;
    }

    // ---- Pauli contraction: 8 strings per lane ----
    const float b2 = sel3(p0s, Ax[0], Ay[0], Az[0]) *
                     sel3(p1s, Ax[1], Ay[1], Az[1]);
    const float bv0 = b2 * sel3(p2b,     Ax[2], Ay[2], Az[2]);
    const float bv1 = b2 * sel3(p2b + 1, Ax[2], Ay[2], Az[2]);

    float z[4];
    #pragma unroll
    for (int q = 0; q < 4; ++q) {
      const float s0 = tf[q][0].x + tf[q][0].y * Ax[3] + tf[q][0].z * Ay[3] + tf[q][0].w * Az[3];
      const float s1 = tf[q][1].x + tf[q][1].y * Ax[3] + tf[q][1].z * Ay[3] + tf[q][1].w * Az[3];
      z[q] = bv0 * s0 + bv1 * s1;
    }
    #pragma unroll
    for (int off = 1; off < 32; off <<= 1) {
      #pragma unroll
      for (int q = 0; q < 4; ++q) z[q] += __shfl_xor(z[q], off, 64);
    }

    // ---- epilogue: out = x + z @ Wout^T + b_out ----
    float4 o0, o1;
    o0.x = xv0.x + boutf[0].x + z[0] * woutf[0][0].x + z[1] * woutf[0][0].y + z[2] * woutf[0][0].z + z[3] * woutf[0][0].w;
    o0.y = xv0.y + boutf[0].y + z[0] * woutf[0][1].x + z[1] * woutf[0][1].y + z[2] * woutf[0][1].z + z[3] * woutf[0][1].w;
    o0.z = xv0.z + boutf[0].z + z[0] * woutf[0][2].x + z[1] * woutf[0][2].y + z[2] * woutf[0][2].z + z[3] * woutf[0][2].w;
    o0.w = xv0.w + boutf[0].w + z[0] * woutf[0][3].x + z[1] * woutf[0][3].y + z[2] * woutf[0][3].z + z[3] * woutf[0][3].w;
    o1.x = xv1.x + boutf[1].x + z[0] * woutf[1][0].x + z[1] * woutf[1][0].y + z[2] * woutf[1][0].z + z[3] * woutf[1][0].w;
    o1.y = xv1.y + boutf[1].y + z[0] * woutf[1][1].x + z[1] * woutf[1][1].y + z[2] * woutf[1][1].z + z[3] * woutf[1][1].w;
    o1.z = xv1.z + boutf[1].z + z[0] * woutf[1][2].x + z[1] * woutf[1][2].y + z[2] * woutf[1][2].z + z[3] * woutf[1][2].w;
    o1.w = xv1.w + boutf[1].w + z[0] * woutf[1][3].x + z[1] * woutf[1][3].y + z[2] * woutf[1][3].z + z[3] * woutf[1][3].w;

    *reinterpret_cast<float4*>(&out[rbase])       = o0;
    *reinterpret_cast<float4*>(&out[rbase + 128]) = o1;

    xv0 = nx0; xv1 = nx1; rbase = nbase;
  }
}

extern "C" void kernel_launch(void* const* d_in, const int* in_sizes, int n_in,
                              void* d_out, int out_size, void* d_ws, size_t ws_size,
                              hipStream_t stream)
{
  const float* x     = (const float*)d_in[0];
  const float* Win   = (const float*)d_in[1];
  const float* b_in  = (const float*)d_in[2];
  const float* gamma = (const float*)d_in[3];
  const float* beta  = (const float*)d_in[4];
  const float* qw    = (const float*)d_in[5];
  const float* Wout  = (const float*)d_in[6];
  const float* b_out = (const float*)d_in[7];
  float* out = (float*)d_out;
  const int B = in_sizes[0] / DIM;

  // 512 blocks = 2 blocks/CU (matches __launch_bounds__(256,2)); grid-stride.
  hipLaunchKernelGGL(qlayer_fused_kernel, dim3(512), dim3(256), 0, stream,
                     x, Win, b_in, gamma, beta, qw, Wout, b_out, out, B);
}